// Round 1
// baseline (181.223 us; speedup 1.0000x reference)
//
#include <hip/hip_runtime.h>

typedef unsigned short u16;
typedef unsigned int   u32;
typedef __attribute__((ext_vector_type(4))) float  f32x4;
typedef __attribute__((ext_vector_type(8))) __bf16 bf16x8;
typedef __attribute__((ext_vector_type(8))) u16    u16x8;
typedef __attribute__((ext_vector_type(4))) u32    u32x4;

#define GLB_AS __attribute__((address_space(1)))
#define LDS_AS __attribute__((address_space(3)))

__device__ __forceinline__ void gload16(const void* g, void* l) {
  __builtin_amdgcn_global_load_lds((const GLB_AS u32*)g, (LDS_AS u32*)l, 16, 0, 0);
}

__device__ __forceinline__ u16 f2bf(float f) {
  u32 x = __builtin_bit_cast(u32, f);
  return (u16)((x + 0x7fffu + ((x >> 16) & 1u)) >> 16);
}
__device__ __forceinline__ float bf2f(u16 h) {
  u32 x = ((u32)h) << 16;
  return __builtin_bit_cast(float, x);
}

// ---------------- cast fp32 -> bf16 ----------------
__global__ void cast_f32_bf16(const float* __restrict__ src, u16* __restrict__ dst, int n4) {
  int i = blockIdx.x * 256 + threadIdx.x;
  if (i >= n4) return;
  float4 v = reinterpret_cast<const float4*>(src)[i];
  ushort4 o;
  o.x = f2bf(v.x); o.y = f2bf(v.y); o.z = f2bf(v.z); o.w = f2bf(v.w);
  reinterpret_cast<ushort4*>(dst)[i] = o;
}

// ---------------- GEMM core: C[128x128] = A[128xK] * B[128xK]^T ----------------
// A,B row-major bf16 with K contiguous. 256 threads = 4 waves (2x2), each wave 64x64.
__device__ __forceinline__ void gemm_core(const u16* __restrict__ Ag, const u16* __restrict__ Bg,
                                          int K, int m0, int n0,
                                          u16* Al, u16* Bl, f32x4 acc[4][4]) {
  const int t = threadIdx.x;
  const int l = t & 63;
  const int c = l & 15, g = l >> 4;
  const int w = t >> 6, wr = w >> 1, wc = w & 1;

#pragma unroll
  for (int mi = 0; mi < 4; mi++)
#pragma unroll
    for (int ni = 0; ni < 4; ni++) acc[mi][ni] = f32x4{0.f, 0.f, 0.f, 0.f};

  for (int k0 = 0; k0 < K; k0 += 32) {
#pragma unroll
    for (int i = 0; i < 2; i++) {
      int idx = i * 256 + t;
      int e   = idx * 8;          // u16 element offset in tile
      int row = e >> 5;           // /32
      int kc  = e & 31;
      gload16(Ag + (size_t)(m0 + row) * K + (k0 + kc), Al + (i * 256 + (t & 192)) * 8);
      gload16(Bg + (size_t)(n0 + row) * K + (k0 + kc), Bl + (i * 256 + (t & 192)) * 8);
    }
    __syncthreads();

    bf16x8 af[4], bfr[4];
#pragma unroll
    for (int mi = 0; mi < 4; mi++)
      af[mi] = *(const bf16x8*)(Al + (wr * 64 + mi * 16 + c) * 32 + g * 8);
#pragma unroll
    for (int ni = 0; ni < 4; ni++)
      bfr[ni] = *(const bf16x8*)(Bl + (wc * 64 + ni * 16 + c) * 32 + g * 8);
#pragma unroll
    for (int mi = 0; mi < 4; mi++)
#pragma unroll
      for (int ni = 0; ni < 4; ni++)
        acc[mi][ni] = __builtin_amdgcn_mfma_f32_16x16x32_bf16(af[mi], bfr[ni], acc[mi][ni], 0, 0, 0);
    __syncthreads();
  }
}

// ---------------- fused QKV projection ----------------
// z=0: Qp[b,s,(h,dk)] = q @ Wq^T + bq   (bf16 flat [4096][1024])
// z=1: Kp likewise
// z=2: Vt[(b,h),dk,s]  = (v @ Wv^T + bv)^T, computed operand-swapped: A=Wv, B=v
__global__ __launch_bounds__(256, 2) void qkv_gemm(
    const u16* __restrict__ qb, const u16* __restrict__ kb, const u16* __restrict__ vb,
    const u16* __restrict__ Wqb, const u16* __restrict__ Wkb, const u16* __restrict__ Wvb,
    const float* __restrict__ bq, const float* __restrict__ bk, const float* __restrict__ bv,
    u16* __restrict__ Qp, u16* __restrict__ Kp, u16* __restrict__ Vt) {
  __shared__ alignas(16) u16 Al[128 * 32];
  __shared__ alignas(16) u16 Bl[128 * 32];
  const int z = blockIdx.z;
  const int bid = blockIdx.x;
  const u16 *Ag, *Bg;
  const float* bias;
  if (z == 0) { Ag = qb; Bg = Wqb; bias = bq; }
  else if (z == 1) { Ag = kb; Bg = Wkb; bias = bk; }
  else { Ag = Wvb; Bg = vb; bias = bv; }
  int mt, nt;
  if (z < 2) { mt = bid >> 3; nt = bid & 7; }
  else       { mt = bid & 7;  nt = bid >> 3; }
  const int m0 = mt * 128, n0 = nt * 128;

  f32x4 acc[4][4];
  gemm_core(Ag, Bg, 1024, m0, n0, Al, Bl, acc);

  const int t = threadIdx.x, l = t & 63, w = t >> 6;
  const int c = l & 15, g = l >> 4, wr = w >> 1, wc = w & 1;
#pragma unroll
  for (int mi = 0; mi < 4; mi++) {
#pragma unroll
    for (int ni = 0; ni < 4; ni++) {
      const int gcol = n0 + wc * 64 + ni * 16 + c;
#pragma unroll
      for (int r = 0; r < 4; r++) {
        const int grow = m0 + wr * 64 + mi * 16 + g * 4 + r;
        float val = acc[mi][ni][r];
        if (z < 2) {
          val += bias[gcol];
          u16* out = (z == 0) ? Qp : Kp;
          out[(size_t)grow * 1024 + gcol] = f2bf(val);
        } else {
          // grow = (h,dk) out-feature, gcol = (b,s)
          val += bias[grow];
          const int hh = grow >> 6, dk = grow & 63, bb = gcol >> 11, ss = gcol & 2047;
          Vt[(((size_t)(bb * 16 + hh) * 64 + dk) << 11) + ss] = f2bf(val);
        }
      }
    }
  }
}

// ---------------- final output projection (fp32 out) ----------------
__global__ __launch_bounds__(256, 2) void out_gemm(
    const u16* __restrict__ AO, const u16* __restrict__ Wob,
    const float* __restrict__ bo, float* __restrict__ out) {
  __shared__ alignas(16) u16 Al[128 * 32];
  __shared__ alignas(16) u16 Bl[128 * 32];
  const int bid = blockIdx.x;
  const int m0 = (bid >> 3) * 128, n0 = (bid & 7) * 128;
  f32x4 acc[4][4];
  gemm_core(AO, Wob, 1024, m0, n0, Al, Bl, acc);
  const int t = threadIdx.x, l = t & 63, w = t >> 6;
  const int c = l & 15, g = l >> 4, wr = w >> 1, wc = w & 1;
#pragma unroll
  for (int mi = 0; mi < 4; mi++)
#pragma unroll
    for (int ni = 0; ni < 4; ni++) {
      const int gcol = n0 + wc * 64 + ni * 16 + c;
      const float bb = bo[gcol];
#pragma unroll
      for (int r = 0; r < 4; r++) {
        const int grow = m0 + wr * 64 + mi * 16 + g * 4 + r;
        out[(size_t)grow * 1024 + gcol] = acc[mi][ni][r] + bb;
      }
    }
}

// ---------------- flash attention ----------------
// Grid (32 q-blocks, 32 (b,h)); 256 threads = 4 waves, each wave owns 16 q-rows.
// Swapped QK^T: st = mfma(K, Q) -> S^T[n][m]; softmax per column m = lane&15.
__global__ __launch_bounds__(256, 2) void attn_fwd(
    const u16* __restrict__ Qb, const u16* __restrict__ Kb,
    const u16* __restrict__ Vt, u16* __restrict__ AO) {
  __shared__ alignas(16) u16 Kl[64 * 64];
  __shared__ alignas(16) u16 Vl[64 * 64];
  const int bh = blockIdx.y, b = bh >> 4, h = bh & 15;
  const int q0 = blockIdx.x * 64;
  const int t = threadIdx.x, w = t >> 6, l = t & 63;
  const int c = l & 15, g = l >> 4;

  // Q fragments (B-operand: j = q-row = c, k = dk), pre-scaled by 1/sqrt(dk)
  bf16x8 qf[2];
  {
    const u16* qp = Qb + ((size_t)(b * 2048 + q0 + w * 16 + c) * 1024 + h * 64 + g * 8);
#pragma unroll
    for (int kk = 0; kk < 2; kk++) {
      u16x8 raw = *(const u16x8*)(qp + kk * 32);
      u16x8 sc;
#pragma unroll
      for (int j = 0; j < 8; j++) sc[j] = f2bf(bf2f(raw[j]) * 0.125f);
      qf[kk] = __builtin_bit_cast(bf16x8, sc);
    }
  }

  f32x4 oacc[4];
#pragma unroll
  for (int d = 0; d < 4; d++) oacc[d] = f32x4{0.f, 0.f, 0.f, 0.f};
  float mrun = -__builtin_inff(), lrun = 0.f;

  for (int kv = 0; kv < 2048; kv += 64) {
    // stage K[64 n][64 dk] and Vt[64 dk][64 s] with XOR-swizzled (16B) source
#pragma unroll
    for (int i = 0; i < 2; i++) {
      int idx  = i * 256 + t;
      int row  = idx >> 3;
      int col8 = ((idx & 7) ^ (row & 7)) * 8;
      gload16(Kb + ((size_t)(b * 2048 + kv + row) * 1024 + h * 64 + col8),
              Kl + (i * 256 + (t & 192)) * 8);
      gload16(Vt + ((size_t)(bh * 64 + row) * 2048 + kv + col8),
              Vl + (i * 256 + (t & 192)) * 8);
    }
    __syncthreads();

    // S^T tile: st[ni][r] = S^T[n = ni*16+g*4+r][m = c]
    f32x4 st[4];
#pragma unroll
    for (int ni = 0; ni < 4; ni++) {
      st[ni] = f32x4{0.f, 0.f, 0.f, 0.f};
#pragma unroll
      for (int kk = 0; kk < 2; kk++) {
        const int krow = ni * 16 + c;
        const int cb   = kk * 64 + g * 16;
        bf16x8 kf = *(const bf16x8*)((const char*)Kl + krow * 128 + (cb ^ ((krow & 7) << 4)));
        st[ni] = __builtin_amdgcn_mfma_f32_16x16x32_bf16(kf, qf[kk], st[ni], 0, 0, 0);
      }
    }

    // online softmax over n for column m=c
    float tmax = -__builtin_inff();
#pragma unroll
    for (int ni = 0; ni < 4; ni++)
#pragma unroll
      for (int r = 0; r < 4; r++) tmax = fmaxf(tmax, st[ni][r]);
    tmax = fmaxf(tmax, __shfl_xor(tmax, 16));
    tmax = fmaxf(tmax, __shfl_xor(tmax, 32));
    const float mnew = fmaxf(mrun, tmax);
    const float f    = __expf(mrun - mnew);
    float tsum = 0.f;
#pragma unroll
    for (int ni = 0; ni < 4; ni++)
#pragma unroll
      for (int r = 0; r < 4; r++) {
        float p = __expf(st[ni][r] - mnew);
        st[ni][r] = p;
        tsum += p;
      }
    tsum += __shfl_xor(tsum, 16);
    tsum += __shfl_xor(tsum, 32);
    lrun = lrun * f + tsum;
    mrun = mnew;

    // pack P^T rows to bf16 pairs: pk01 = (r0,r1), pk23 = (r2,r3)
    u32 pk01[4], pk23[4];
#pragma unroll
    for (int ni = 0; ni < 4; ni++) {
      pk01[ni] = (u32)f2bf(st[ni][0]) | ((u32)f2bf(st[ni][1]) << 16);
      pk23[ni] = (u32)f2bf(st[ni][2]) | ((u32)f2bf(st[ni][3]) << 16);
    }

    // rescale O (factor lives at column lanes; broadcast to row form)
    float fr[4];
#pragma unroll
    for (int r = 0; r < 4; r++) fr[r] = __shfl(f, g * 4 + r);
#pragma unroll
    for (int d = 0; d < 4; d++)
#pragma unroll
      for (int r = 0; r < 4; r++) oacc[d][r] *= fr[r];

    // PV: A-operand = P[m = c][n = kk*32 + g*8 + jj] built via shuffles
#pragma unroll
    for (int kk = 0; kk < 2; kk++) {
      const int sa = ((g & 1) << 5) | c;
      const int ti = g >> 1;  // which ni tile of the (2kk, 2kk+1) pair
      u32 w0a = __shfl(pk01[2 * kk], sa),      w0b = __shfl(pk01[2 * kk + 1], sa);
      u32 w1a = __shfl(pk23[2 * kk], sa),      w1b = __shfl(pk23[2 * kk + 1], sa);
      u32 w2a = __shfl(pk01[2 * kk], sa + 16), w2b = __shfl(pk01[2 * kk + 1], sa + 16);
      u32 w3a = __shfl(pk23[2 * kk], sa + 16), w3b = __shfl(pk23[2 * kk + 1], sa + 16);
      u32x4 wv;
      wv.x = ti ? w0b : w0a;
      wv.y = ti ? w1b : w1a;
      wv.z = ti ? w2b : w2a;
      wv.w = ti ? w3b : w3a;
      bf16x8 pa = __builtin_bit_cast(bf16x8, wv);
#pragma unroll
      for (int d = 0; d < 4; d++) {
        const int vrow = d * 16 + c;
        const int cb   = kk * 64 + g * 16;
        bf16x8 vf = *(const bf16x8*)((const char*)Vl + vrow * 128 + (cb ^ ((vrow & 7) << 4)));
        oacc[d] = __builtin_amdgcn_mfma_f32_16x16x32_bf16(pa, vf, oacc[d], 0, 0, 0);
      }
    }
    __syncthreads();
  }

  // epilogue: divide by l (broadcast to row form) and store bf16
  float li[4];
#pragma unroll
  for (int r = 0; r < 4; r++) li[r] = 1.f / __shfl(lrun, g * 4 + r);
#pragma unroll
  for (int d = 0; d < 4; d++)
#pragma unroll
    for (int r = 0; r < 4; r++) {
      size_t addr = (size_t)(b * 2048 + q0 + w * 16 + g * 4 + r) * 1024 + h * 64 + d * 16 + c;
      AO[addr] = f2bf(oacc[d][r] * li[r]);
    }
}

// ---------------- launch ----------------
extern "C" void kernel_launch(void* const* d_in, const int* in_sizes, int n_in,
                              void* d_out, int out_size, void* d_ws, size_t ws_size,
                              hipStream_t stream) {
  const float* q  = (const float*)d_in[0];
  const float* k  = (const float*)d_in[1];
  const float* v  = (const float*)d_in[2];
  const float* Wq = (const float*)d_in[3];
  const float* bq = (const float*)d_in[4];
  const float* Wk = (const float*)d_in[5];
  const float* bk = (const float*)d_in[6];
  const float* Wv = (const float*)d_in[7];
  const float* bv = (const float*)d_in[8];
  const float* Wo = (const float*)d_in[9];
  const float* bo = (const float*)d_in[10];

  char* ws = (char*)d_ws;
  const size_t MB = 1u << 20;
  u16* qb  = (u16*)(ws + 0 * MB);   // 8 MB each for activations
  u16* kb  = (u16*)(ws + 8 * MB);
  u16* vb  = (u16*)(ws + 16 * MB);
  u16* Wqb = (u16*)(ws + 24 * MB);  // 2 MB each for weights
  u16* Wkb = (u16*)(ws + 26 * MB);
  u16* Wvb = (u16*)(ws + 28 * MB);
  u16* Wob = (u16*)(ws + 30 * MB);
  u16* Qp  = (u16*)(ws + 32 * MB);
  u16* Kp  = (u16*)(ws + 40 * MB);
  u16* Vtp = (u16*)(ws + 48 * MB);
  u16* AO  = (u16*)(ws + 56 * MB);

  cast_f32_bf16<<<4096, 256, 0, stream>>>(q, qb, 1048576);
  cast_f32_bf16<<<4096, 256, 0, stream>>>(k, kb, 1048576);
  cast_f32_bf16<<<4096, 256, 0, stream>>>(v, vb, 1048576);
  cast_f32_bf16<<<1024, 256, 0, stream>>>(Wq, Wqb, 262144);
  cast_f32_bf16<<<1024, 256, 0, stream>>>(Wk, Wkb, 262144);
  cast_f32_bf16<<<1024, 256, 0, stream>>>(Wv, Wvb, 262144);
  cast_f32_bf16<<<1024, 256, 0, stream>>>(Wo, Wob, 262144);

  qkv_gemm<<<dim3(256, 1, 3), 256, 0, stream>>>(qb, kb, vb, Wqb, Wkb, Wvb,
                                                bq, bk, bv, Qp, Kp, Vtp);
  attn_fwd<<<dim3(32, 32), 256, 0, stream>>>(Qp, Kp, Vtp, AO);
  out_gemm<<<256, 256, 0, stream>>>(AO, Wob, bo, (float*)d_out);
}

// Round 2
// 148.190 us; speedup vs baseline: 1.2229x; 1.2229x over previous
//
#include <hip/hip_runtime.h>

typedef unsigned short u16;
typedef unsigned int   u32;
typedef __attribute__((ext_vector_type(4))) float  f32x4;
typedef __attribute__((ext_vector_type(8))) __bf16 bf16x8;
typedef __attribute__((ext_vector_type(8))) u16    u16x8;
typedef __attribute__((ext_vector_type(2))) u32    u32x2;

#define GLB_AS __attribute__((address_space(1)))
#define LDS_AS __attribute__((address_space(3)))

__device__ __forceinline__ void gload16(const void* g, void* l) {
  __builtin_amdgcn_global_load_lds((const GLB_AS u32*)g, (LDS_AS u32*)l, 16, 0, 0);
}

__device__ __forceinline__ u16 f2bf(float f) {
  u32 x = __builtin_bit_cast(u32, f);
  return (u16)((x + 0x7fffu + ((x >> 16) & 1u)) >> 16);
}
__device__ __forceinline__ float bf2f(u16 h) {
  u32 x = ((u32)h) << 16;
  return __builtin_bit_cast(float, x);
}
// packed f32x2 -> bf16x2 (RNE), lo = a, hi = b  (T12 recipe; no builtin on gfx950)
__device__ __forceinline__ u32 cvtpk_bf16(float a, float b) {
  u32 r;
  asm("v_cvt_pk_bf16_f32 %0, %1, %2" : "=v"(r) : "v"(a), "v"(b));
  return r;
}

// ---------------- fused cast fp32 -> bf16 (all 7 arrays, one launch) ----------------
__global__ void cast_all(const float* __restrict__ q, const float* __restrict__ k,
                         const float* __restrict__ v, const float* __restrict__ Wq,
                         const float* __restrict__ Wk, const float* __restrict__ Wv,
                         const float* __restrict__ Wo,
                         u16* __restrict__ qb, u16* __restrict__ kb, u16* __restrict__ vb,
                         u16* __restrict__ Wqb, u16* __restrict__ Wkb, u16* __restrict__ Wvb,
                         u16* __restrict__ Wob) {
  int i = blockIdx.x * 256 + threadIdx.x;     // float4 index; total 4,194,304
  const float* src;
  u16* dst;
  int off;
  if (i < 3145728) {                          // q,k,v: 1,048,576 float4 each
    int seg = i >> 20;
    off = i & 1048575;
    src = seg == 0 ? q : seg == 1 ? k : v;
    dst = seg == 0 ? qb : seg == 1 ? kb : vb;
  } else {                                    // weights: 262,144 float4 each
    int wi = i - 3145728;
    int seg = wi >> 18;
    off = wi & 262143;
    src = seg == 0 ? Wq : seg == 1 ? Wk : seg == 2 ? Wv : Wo;
    dst = seg == 0 ? Wqb : seg == 1 ? Wkb : seg == 2 ? Wvb : Wob;
  }
  float4 f = reinterpret_cast<const float4*>(src)[off];
  ushort4 o;
  o.x = f2bf(f.x); o.y = f2bf(f.y); o.z = f2bf(f.z); o.w = f2bf(f.w);
  reinterpret_cast<ushort4*>(dst)[off] = o;
}

// ---------------- GEMM core: C[128x128] = A[128xK] * B[128xK]^T ----------------
__device__ __forceinline__ void gemm_core(const u16* __restrict__ Ag, const u16* __restrict__ Bg,
                                          int K, int m0, int n0,
                                          u16* Al, u16* Bl, f32x4 acc[4][4]) {
  const int t = threadIdx.x;
  const int l = t & 63;
  const int c = l & 15, g = l >> 4;
  const int w = t >> 6, wr = w >> 1, wc = w & 1;

#pragma unroll
  for (int mi = 0; mi < 4; mi++)
#pragma unroll
    for (int ni = 0; ni < 4; ni++) acc[mi][ni] = f32x4{0.f, 0.f, 0.f, 0.f};

  for (int k0 = 0; k0 < K; k0 += 32) {
#pragma unroll
    for (int i = 0; i < 2; i++) {
      int idx = i * 256 + t;
      int e   = idx * 8;
      int row = e >> 5;
      int kc  = e & 31;
      gload16(Ag + (size_t)(m0 + row) * K + (k0 + kc), Al + (i * 256 + (t & 192)) * 8);
      gload16(Bg + (size_t)(n0 + row) * K + (k0 + kc), Bl + (i * 256 + (t & 192)) * 8);
    }
    __syncthreads();

    bf16x8 af[4], bfr[4];
#pragma unroll
    for (int mi = 0; mi < 4; mi++)
      af[mi] = *(const bf16x8*)(Al + (wr * 64 + mi * 16 + c) * 32 + g * 8);
#pragma unroll
    for (int ni = 0; ni < 4; ni++)
      bfr[ni] = *(const bf16x8*)(Bl + (wc * 64 + ni * 16 + c) * 32 + g * 8);
#pragma unroll
    for (int mi = 0; mi < 4; mi++)
#pragma unroll
      for (int ni = 0; ni < 4; ni++)
        acc[mi][ni] = __builtin_amdgcn_mfma_f32_16x16x32_bf16(af[mi], bfr[ni], acc[mi][ni], 0, 0, 0);
    __syncthreads();
  }
}

// ---------------- fused QKV projection ----------------
__global__ __launch_bounds__(256, 2) void qkv_gemm(
    const u16* __restrict__ qb, const u16* __restrict__ kb, const u16* __restrict__ vb,
    const u16* __restrict__ Wqb, const u16* __restrict__ Wkb, const u16* __restrict__ Wvb,
    const float* __restrict__ bq, const float* __restrict__ bk, const float* __restrict__ bv,
    u16* __restrict__ Qp, u16* __restrict__ Kp, u16* __restrict__ Vt) {
  __shared__ alignas(16) u16 Al[128 * 32];
  __shared__ alignas(16) u16 Bl[128 * 32];
  const int z = blockIdx.z;
  const int bid = blockIdx.x;
  const u16 *Ag, *Bg;
  const float* bias;
  if (z == 0) { Ag = qb; Bg = Wqb; bias = bq; }
  else if (z == 1) { Ag = kb; Bg = Wkb; bias = bk; }
  else { Ag = Wvb; Bg = vb; bias = bv; }
  int mt, nt;
  if (z < 2) { mt = bid >> 3; nt = bid & 7; }
  else       { mt = bid & 7;  nt = bid >> 3; }
  const int m0 = mt * 128, n0 = nt * 128;

  f32x4 acc[4][4];
  gemm_core(Ag, Bg, 1024, m0, n0, Al, Bl, acc);

  const int t = threadIdx.x, l = t & 63, w = t >> 6;
  const int c = l & 15, g = l >> 4, wr = w >> 1, wc = w & 1;
#pragma unroll
  for (int mi = 0; mi < 4; mi++) {
#pragma unroll
    for (int ni = 0; ni < 4; ni++) {
      const int gcol = n0 + wc * 64 + ni * 16 + c;
#pragma unroll
      for (int r = 0; r < 4; r++) {
        const int grow = m0 + wr * 64 + mi * 16 + g * 4 + r;
        float val = acc[mi][ni][r];
        if (z < 2) {
          val += bias[gcol];
          u16* out = (z == 0) ? Qp : Kp;
          out[(size_t)grow * 1024 + gcol] = f2bf(val);
        } else {
          val += bias[grow];
          const int hh = grow >> 6, dk = grow & 63, bb = gcol >> 11, ss = gcol & 2047;
          Vt[(((size_t)(bb * 16 + hh) * 64 + dk) << 11) + ss] = f2bf(val);
        }
      }
    }
  }
}

// ---------------- final output projection (fp32 out) ----------------
__global__ __launch_bounds__(256, 2) void out_gemm(
    const u16* __restrict__ AO, const u16* __restrict__ Wob,
    const float* __restrict__ bo, float* __restrict__ out) {
  __shared__ alignas(16) u16 Al[128 * 32];
  __shared__ alignas(16) u16 Bl[128 * 32];
  const int bid = blockIdx.x;
  const int m0 = (bid >> 3) * 128, n0 = (bid & 7) * 128;
  f32x4 acc[4][4];
  gemm_core(AO, Wob, 1024, m0, n0, Al, Bl, acc);
  const int t = threadIdx.x, l = t & 63, w = t >> 6;
  const int c = l & 15, g = l >> 4, wr = w >> 1, wc = w & 1;
#pragma unroll
  for (int mi = 0; mi < 4; mi++)
#pragma unroll
    for (int ni = 0; ni < 4; ni++) {
      const int gcol = n0 + wc * 64 + ni * 16 + c;
      const float bb = bo[gcol];
#pragma unroll
      for (int r = 0; r < 4; r++) {
        const int grow = m0 + wr * 64 + mi * 16 + g * 4 + r;
        out[(size_t)grow * 1024 + gcol] = acc[mi][ni][r] + bb;
      }
    }
}

// ---------------- flash attention (v2: log2-domain softmax, defer-max, P via LDS) ----
// Grid (32 q-blocks, 32 (b,h)); 256 threads = 4 waves, each wave owns 16 q-rows.
// Swapped QK^T: st = mfma(K, Q) -> S^T[n][m]; scores are in log2 units.
// P redistribution to PV A-fragment layout goes through a per-wave 2KB LDS buffer
// (XOR-swizzled, same involution on write and read; 2-way conflicts = free).
__global__ __launch_bounds__(256, 2) void attn_fwd(
    const u16* __restrict__ Qb, const u16* __restrict__ Kb,
    const u16* __restrict__ Vt, u16* __restrict__ AO) {
  __shared__ alignas(16) u16 Kl[64 * 64];
  __shared__ alignas(16) u16 Vl[64 * 64];
  __shared__ alignas(16) u16 Pl[4][16 * 64];   // per-wave P[q=16][n=64]
  const int bh = blockIdx.y, b = bh >> 4, h = bh & 15;
  const int q0 = blockIdx.x * 64;
  const int t = threadIdx.x, w = t >> 6, l = t & 63;
  const int c = l & 15, g = l >> 4;
  char* Pw = (char*)Pl[w];
  const int swz = (c & 7) << 4;

  // Q fragments, pre-scaled by log2(e)/sqrt(dk)
  const float QSCALE = 0.125f * 1.44269504f;
  bf16x8 qf[2];
  {
    const u16* qp = Qb + ((size_t)(b * 2048 + q0 + w * 16 + c) * 1024 + h * 64 + g * 8);
#pragma unroll
    for (int kk = 0; kk < 2; kk++) {
      u16x8 raw = *(const u16x8*)(qp + kk * 32);
      u16x8 sc;
#pragma unroll
      for (int j = 0; j < 8; j++) sc[j] = f2bf(bf2f(raw[j]) * QSCALE);
      qf[kk] = __builtin_bit_cast(bf16x8, sc);
    }
  }

  f32x4 oacc[4];
#pragma unroll
  for (int d = 0; d < 4; d++) oacc[d] = f32x4{0.f, 0.f, 0.f, 0.f};
  float mrun = -3.0e38f, lrun = 0.f;
  const float THR = 11.54f;   // 8 nats in log2 units

  for (int kv = 0; kv < 2048; kv += 64) {
    // stage K[64 n][64 dk] and Vt[64 dk][64 s], XOR-swizzled global source
#pragma unroll
    for (int i = 0; i < 2; i++) {
      int idx  = i * 256 + t;
      int row  = idx >> 3;
      int col8 = ((idx & 7) ^ (row & 7)) * 8;
      gload16(Kb + ((size_t)(b * 2048 + kv + row) * 1024 + h * 64 + col8),
              Kl + (i * 256 + (t & 192)) * 8);
      gload16(Vt + ((size_t)(bh * 64 + row) * 2048 + kv + col8),
              Vl + (i * 256 + (t & 192)) * 8);
    }
    __syncthreads();

    // S^T tile (log2 units): st[ni][r] = S^T[n = ni*16+g*4+r][m = c]
    f32x4 st[4];
#pragma unroll
    for (int ni = 0; ni < 4; ni++) {
      st[ni] = f32x4{0.f, 0.f, 0.f, 0.f};
#pragma unroll
      for (int kk = 0; kk < 2; kk++) {
        const int krow = ni * 16 + c;
        const int cb   = kk * 64 + g * 16;
        bf16x8 kf = *(const bf16x8*)((const char*)Kl + krow * 128 + (cb ^ ((krow & 7) << 4)));
        st[ni] = __builtin_amdgcn_mfma_f32_16x16x32_bf16(kf, qf[kk], st[ni], 0, 0, 0);
      }
    }

    // column max (per q = c)
    float tmax = -3.0e38f;
#pragma unroll
    for (int ni = 0; ni < 4; ni++)
#pragma unroll
      for (int r = 0; r < 4; r++) tmax = fmaxf(tmax, st[ni][r]);
    tmax = fmaxf(tmax, __shfl_xor(tmax, 16));
    tmax = fmaxf(tmax, __shfl_xor(tmax, 32));

    // defer-max: only rescale when the running max grew by more than THR
    if (__any(tmax > mrun + THR)) {
      const float mnew = fmaxf(mrun, tmax);
      const float f    = __builtin_amdgcn_exp2f(mrun - mnew);
      float fr[4];
#pragma unroll
      for (int r = 0; r < 4; r++) fr[r] = __shfl(f, g * 4 + r);
#pragma unroll
      for (int d = 0; d < 4; d++)
#pragma unroll
        for (int r = 0; r < 4; r++) oacc[d][r] *= fr[r];
      lrun *= f;
      mrun = mnew;
    }

    // P = exp2(st - mrun), row sum, pack to bf16, write to per-wave LDS
    float tsum = 0.f;
#pragma unroll
    for (int ni = 0; ni < 4; ni++) {
      float p0 = __builtin_amdgcn_exp2f(st[ni][0] - mrun);
      float p1 = __builtin_amdgcn_exp2f(st[ni][1] - mrun);
      float p2 = __builtin_amdgcn_exp2f(st[ni][2] - mrun);
      float p3 = __builtin_amdgcn_exp2f(st[ni][3] - mrun);
      tsum += (p0 + p1) + (p2 + p3);
      u32x2 pk;
      pk.x = cvtpk_bf16(p0, p1);
      pk.y = cvtpk_bf16(p2, p3);
      // P[q=c][n=ni*16+g*4 .. +3] -> byte c*128 + (ni*32+g*8) ^ swz  (8B aligned)
      *(u32x2*)(Pw + c * 128 + ((ni * 32 + g * 8) ^ swz)) = pk;
    }
    tsum += __shfl_xor(tsum, 16);
    tsum += __shfl_xor(tsum, 32);
    lrun += tsum;

    asm volatile("" ::: "memory");  // keep P-writes ordered before PV reads

    // PV: A = P[q = c][n], read back from per-wave LDS (same swizzle)
#pragma unroll
    for (int kk = 0; kk < 2; kk++) {
      bf16x8 pa = *(const bf16x8*)(Pw + c * 128 + ((kk * 64 + g * 16) ^ swz));
#pragma unroll
      for (int d = 0; d < 4; d++) {
        const int vrow = d * 16 + c;
        const int cb   = kk * 64 + g * 16;
        bf16x8 vf = *(const bf16x8*)((const char*)Vl + vrow * 128 + (cb ^ ((vrow & 7) << 4)));
        oacc[d] = __builtin_amdgcn_mfma_f32_16x16x32_bf16(pa, vf, oacc[d], 0, 0, 0);
      }
    }
    __syncthreads();
  }

  // epilogue: divide by l (broadcast to row form) and store bf16
  float li[4];
#pragma unroll
  for (int r = 0; r < 4; r++) li[r] = 1.f / __shfl(lrun, g * 4 + r);
#pragma unroll
  for (int d = 0; d < 4; d++)
#pragma unroll
    for (int r = 0; r < 4; r++) {
      size_t addr = (size_t)(b * 2048 + q0 + w * 16 + g * 4 + r) * 1024 + h * 64 + d * 16 + c;
      AO[addr] = f2bf(oacc[d][r] * li[r]);
    }
}

// ---------------- launch ----------------
extern "C" void kernel_launch(void* const* d_in, const int* in_sizes, int n_in,
                              void* d_out, int out_size, void* d_ws, size_t ws_size,
                              hipStream_t stream) {
  const float* q  = (const float*)d_in[0];
  const float* k  = (const float*)d_in[1];
  const float* v  = (const float*)d_in[2];
  const float* Wq = (const float*)d_in[3];
  const float* bq = (const float*)d_in[4];
  const float* Wk = (const float*)d_in[5];
  const float* bk = (const float*)d_in[6];
  const float* Wv = (const float*)d_in[7];
  const float* bv = (const float*)d_in[8];
  const float* Wo = (const float*)d_in[9];
  const float* bo = (const float*)d_in[10];

  char* ws = (char*)d_ws;
  const size_t MB = 1u << 20;
  u16* qb  = (u16*)(ws + 0 * MB);
  u16* kb  = (u16*)(ws + 8 * MB);
  u16* vb  = (u16*)(ws + 16 * MB);
  u16* Wqb = (u16*)(ws + 24 * MB);
  u16* Wkb = (u16*)(ws + 26 * MB);
  u16* Wvb = (u16*)(ws + 28 * MB);
  u16* Wob = (u16*)(ws + 30 * MB);
  u16* Qp  = (u16*)(ws + 32 * MB);
  u16* Kp  = (u16*)(ws + 40 * MB);
  u16* Vtp = (u16*)(ws + 48 * MB);
  u16* AO  = (u16*)(ws + 56 * MB);

  cast_all<<<16384, 256, 0, stream>>>(q, k, v, Wq, Wk, Wv, Wo,
                                      qb, kb, vb, Wqb, Wkb, Wvb, Wob);
  qkv_gemm<<<dim3(256, 1, 3), 256, 0, stream>>>(qb, kb, vb, Wqb, Wkb, Wvb,
                                                bq, bk, bv, Qp, Kp, Vtp);
  attn_fwd<<<dim3(32, 32), 256, 0, stream>>>(Qp, Kp, Vtp, AO);
  out_gemm<<<256, 256, 0, stream>>>(AO, Wob, bo, (float*)d_out);
}